// Round 14
// baseline (301.151 us; speedup 1.0000x reference)
//
#include <hip/hip_runtime.h>
#include <hip/hip_bf16.h>
#include <stdint.h>

// ---------------- types / helpers ----------------
typedef __bf16 b16x8 __attribute__((ext_vector_type(8)));
typedef float  f32x4 __attribute__((ext_vector_type(4)));

__device__ __forceinline__ unsigned short f2bf(float f) {
    uint32_t u = __float_as_uint(f);
    u += 0x7fffu + ((u >> 16) & 1u);   // RNE
    return (unsigned short)(u >> 16);
}
__device__ __forceinline__ float bf2f(unsigned short s) {
    return __uint_as_float(((uint32_t)s) << 16);
}

__device__ __forceinline__ void gld16(const unsigned short* g, unsigned short* l) {
    __builtin_amdgcn_global_load_lds(
        (const __attribute__((address_space(1))) void*)g,
        (__attribute__((address_space(3))) void*)l, 16, 0, 0);
}

// convert/copy one 8-elem chunk (16B bf16 out)
__device__ __forceinline__ void cvt_chunk(const void* src, unsigned short* dst,
                                          long off, int fl) {
    if (fl) {
        const float4* s = (const float4*)src + 2 * off;
        float4 a = s[0], b = s[1];
        uint4 o;
        o.x = f2bf(a.x) | ((uint32_t)f2bf(a.y) << 16);
        o.y = f2bf(a.z) | ((uint32_t)f2bf(a.w) << 16);
        o.z = f2bf(b.x) | ((uint32_t)f2bf(b.y) << 16);
        o.w = f2bf(b.z) | ((uint32_t)f2bf(b.w) << 16);
        ((uint4*)dst)[off] = o;
    } else {
        ((uint4*)dst)[off] = ((const uint4*)src)[off];
    }
}

// ---------------- prep: flag + biases + weights + k/q/v cvt (1 dispatch) ---
__global__ __launch_bounds__(256) void k_prep(
    const void* __restrict__ q_in, const void* __restrict__ k_in,
    const void* __restrict__ v_in,
    const void* Wq, const void* bq, const void* Wk, const void* bk,
    const void* Wv, const void* bv, const void* Wo, const void* bo,
    unsigned short* __restrict__ wqb, unsigned short* __restrict__ wkb,
    unsigned short* __restrict__ wvb, unsigned short* __restrict__ wob,
    float* __restrict__ bias4,
    unsigned short* __restrict__ kb, unsigned short* __restrict__ qb,
    unsigned short* __restrict__ vb, int* __restrict__ flag)
{
    float m = 0.f;
    const unsigned short* qraw = (const unsigned short*)q_in;
    for (int i = threadIdx.x; i < 4096; i += 256) {
        float f = fabsf(bf2f(qraw[i]));
        if (!(f < 1e30f)) f = 1e30f;
        m = fmaxf(m, f);
    }
#pragma unroll
    for (int o = 32; o > 0; o >>= 1) m = fmaxf(m, __shfl_xor(m, o));
    __shared__ float red[4];
    if ((threadIdx.x & 63) == 0) red[threadIdx.x >> 6] = m;
    __syncthreads();
    m = fmaxf(fmaxf(red[0], red[1]), fmaxf(red[2], red[3]));
    const int fl = (m > 1e6f) ? 1 : 0;   // 1 => inputs are f32
    if (blockIdx.x == 0 && threadIdx.x == 0) flag[0] = fl;

    if (blockIdx.x < 16) {   // biases -> f32
        int i = blockIdx.x * 256 + threadIdx.x;
        int which = i >> 10, idx = i & 1023;
        const void* src = (which == 0) ? bq : (which == 1) ? bk : (which == 2) ? bv : bo;
        bias4[i] = fl ? ((const float*)src)[idx] : bf2f(((const unsigned short*)src)[idx]);
    }

    const long NW = 65536L + 3 * 131072L;   // weight 8-elem chunks
    for (long c = blockIdx.x * 256L + threadIdx.x; c < NW; c += (long)gridDim.x * 256L) {
        if (c < 65536)       cvt_chunk(Wq, wqb, c, fl);
        else if (c < 196608) cvt_chunk(Wk, wkb, c - 65536, fl);
        else if (c < 327680) cvt_chunk(Wv, wvb, c - 196608, fl);
        else                 cvt_chunk(Wo, wob, c - 327680, fl);
    }

    const long KN8 = 2097152, QN8 = 1048576, VN8 = 2097152;
    const long TOT = KN8 + QN8 + VN8;
    for (long c = blockIdx.x * 256L + threadIdx.x; c < TOT; c += (long)gridDim.x * 256L) {
        if (c < KN8)            cvt_chunk(k_in, kb, c, fl);
        else if (c < KN8 + QN8) cvt_chunk(q_in, qb, c - KN8, fl);
        else                    cvt_chunk(v_in, vb, c - KN8 - QN8, fl);
    }
}

// ---------------- 256x256 GEMM core: BK=32 quad-buffer, depth-3 prefetch ---
// 4 LDS slots x (A 256x32 + B 256x32) bf16 = 128 KB. Per step t:
//   stage(t+3) -> vmcnt(12|8|4|0) gate ("memory" asm = compiler mem fence)
//   -> sched_barrier(0xF): ALU/VALU/SALU/MFMA may cross, memory may NOT
//   -> s_barrier -> ds_read frags -> setprio(1) 32 MFMA setprio(0)
//   -> sched_barrier(0xF) -> s_barrier.
// Correctness identical to round-7's validated k_gemmD (slot (t+3)&3 last read
// in iter t-1, one barrier before overwrite issue; gates keep all waves' loads
// landed before reads). Only the scheduling fences are relaxed (m141).
__device__ __forceinline__ void gemm256(
    const unsigned short* __restrict__ Ab, const unsigned short* __restrict__ Bb,
    const float* __restrict__ bias, void* __restrict__ Cv,
    int N, int K, int ldA, int ldB, int Mb, int am0, long zC, int bn,
    float scale, int mode, int fl, unsigned short* lds)
{
    const int tid  = threadIdx.x;
    const int lane = tid & 63;
    const int wave = tid >> 6;
    const int g  = wave >> 2;            // M-group: rows g*128..g*128+127
    const int wn = (wave & 3) * 64;      // N base

    f32x4 acc[8][4];
    const f32x4 zero = {0.f, 0.f, 0.f, 0.f};
#pragma unroll
    for (int i = 0; i < 8; ++i)
#pragma unroll
        for (int j = 0; j < 4; ++j) acc[i][j] = zero;

    // stage K-step t into slot t&3 (4 gld16/thread: A,B,A,B)
    auto stageD = [&](int t) {
        unsigned short* S = lds + (size_t)(t & 3) * 16384;
#pragma unroll
        for (int j = 0; j < 2; ++j) {
            const int c = j * 512 + tid;
            const int row = c >> 2;
            const int klo = (c & 3) ^ ((row >> 1) & 3);
            gld16(Ab + (long)(am0 + row) * ldA + t * 32 + klo * 8, S + (size_t)c * 8);
            gld16(Bb + (long)(bn + row) * ldB + t * 32 + klo * 8, S + 8192 + (size_t)c * 8);
        }
    };

    const int NT = K >> 5;
    stageD(0); stageD(1); stageD(2);     // depth-3 prologue (12 loads)

    const int kl = lane >> 4;            // 0..3 -> k chunk
    for (int t = 0; t < NT; ++t) {
        if (t + 3 < NT) stageD(t + 3);
        // counted gate: wait only step t's loads (3 stages = 12 in flight)
        if (t + 3 < NT)      asm volatile("s_waitcnt vmcnt(12)" ::: "memory");
        else if (t + 2 < NT) asm volatile("s_waitcnt vmcnt(8)"  ::: "memory");
        else if (t + 1 < NT) asm volatile("s_waitcnt vmcnt(4)"  ::: "memory");
        else                 asm volatile("s_waitcnt vmcnt(0)"  ::: "memory");
        __builtin_amdgcn_sched_barrier(0x0F);   // mem ops pinned, ALU free
        __builtin_amdgcn_s_barrier();           // all waves' step-t data in LDS
        __builtin_amdgcn_sched_barrier(0x0F);
        const unsigned short* SA = lds + (size_t)(t & 3) * 16384;
        const unsigned short* SB = SA + 8192;
        b16x8 af[8], bf[4];
#pragma unroll
        for (int j = 0; j < 4; ++j) {
            const int r = wn + j * 16 + (lane & 15);
            bf[j] = *(const b16x8*)(SB + ((size_t)r * 4 + (kl ^ ((r >> 1) & 3))) * 8);
        }
#pragma unroll
        for (int i = 0; i < 8; ++i) {
            const int r = g * 128 + i * 16 + (lane & 15);
            af[i] = *(const b16x8*)(SA + ((size_t)r * 4 + (kl ^ ((r >> 1) & 3))) * 8);
        }
        __builtin_amdgcn_s_setprio(1);
#pragma unroll
        for (int i = 0; i < 8; ++i)
#pragma unroll
            for (int j = 0; j < 4; ++j)
                acc[i][j] = __builtin_amdgcn_mfma_f32_16x16x32_bf16(af[i], bf[j], acc[i][j], 0, 0, 0);
        __builtin_amdgcn_s_setprio(0);
        __builtin_amdgcn_sched_barrier(0x0F);
        __builtin_amdgcn_s_barrier();           // step-t reads done -> slot reusable
        __builtin_amdgcn_sched_barrier(0x0F);
    }

#pragma unroll
    for (int i = 0; i < 8; ++i)
#pragma unroll
        for (int j = 0; j < 4; ++j) {
            const int rloc = am0 + g * 128 + i * 16 + (lane >> 4) * 4;
            const int n    = bn + wn + j * 16 + (lane & 15);
            const float bv = (mode != 2 && bias != nullptr) ? bias[n] : 0.f;
            if (mode == 0) {
                unsigned short* C = (unsigned short*)Cv;
#pragma unroll
                for (int r = 0; r < 4; ++r)
                    C[zC + (long)(rloc + r) * N + n] = f2bf(acc[i][j][r] * scale + bv);
            } else if (mode == 1) {
                unsigned short* C = (unsigned short*)Cv;
                uint32_t p0 = f2bf(acc[i][j][0] * scale + bv) |
                              ((uint32_t)f2bf(acc[i][j][1] * scale + bv) << 16);
                uint32_t p1 = f2bf(acc[i][j][2] * scale + bv) |
                              ((uint32_t)f2bf(acc[i][j][3] * scale + bv) << 16);
                uint2 val; val.x = p0; val.y = p1;
                *(uint2*)(C + zC + (long)n * Mb + rloc) = val;
            } else if (mode == 2) {
                float* C = (float*)Cv;
#pragma unroll
                for (int r = 0; r < 4; ++r)
                    C[zC + (long)(rloc + r) * N + n] = acc[i][j][r] * scale;
            } else {
                if (fl) {
                    float* C = (float*)Cv;
#pragma unroll
                    for (int r = 0; r < 4; ++r)
                        C[zC + (long)(rloc + r) * N + n] = acc[i][j][r] * scale + bv;
                } else {
                    unsigned short* C = (unsigned short*)Cv;
#pragma unroll
                    for (int r = 0; r < 4; ++r)
                        C[zC + (long)(rloc + r) * N + n] = f2bf(acc[i][j][r] * scale + bv);
                }
            }
        }
}

// ---------------- merged K/Q/V projections: 768 blocks, 1 dispatch ---------
__global__ __launch_bounds__(512, 2) void k_proj3(
    const unsigned short* __restrict__ kb, const unsigned short* __restrict__ qb,
    const unsigned short* __restrict__ vb,
    const unsigned short* __restrict__ wkb, const unsigned short* __restrict__ wqb,
    const unsigned short* __restrict__ wvb,
    const float* __restrict__ bias4,
    unsigned short* __restrict__ Kt, unsigned short* __restrict__ Qt,
    unsigned short* __restrict__ Vp)
{
    extern __shared__ unsigned short lds_raw[];
    const int nwg = gridDim.x * gridDim.y;            // 768
    const int bid = blockIdx.y * gridDim.x + blockIdx.x;
    const int vbk = (bid & 7) * (nwg >> 3) + (bid >> 3);
    const int sec = vbk >> 8;                         // 0:K 1:Q 2:V
    const int wi  = vbk & 255;
    const int bn  = (wi & 3) * 256;
    const int bm  = (wi >> 2) * 256;
    if (sec == 0) {
        const int batch = bm >> 11, am0 = bm & 2047;
        gemm256(kb + (long)batch * 2048 * 1024, wkb, bias4 + 1024, Kt,
                1024, 1024, 1024, 1024, 2048, am0, (long)batch * 1024 * 2048, bn,
                1.f, 1, 0, lds_raw);
    } else if (sec == 1) {
        const int batch = bm >> 11, am0 = bm & 2047;
        gemm256(qb + (long)batch * 2048 * 512, wqb, bias4, Qt,
                1024, 512, 512, 512, 2048, am0, (long)batch * 1024 * 2048, bn,
                1.f, 1, 0, lds_raw);
    } else {
        gemm256(vb, wvb, bias4 + 2 * 1024, Vp,
                1024, 1024, 1024, 1024, 16384, bm, 0, bn,
                1.f, 0, 0, lds_raw);                  // in-place (co-start timing-safe)
    }
}

// ---------------- attn and out (new core) ----------------
__global__ __launch_bounds__(512, 2) void k_attn(
    const unsigned short* __restrict__ Vp, const unsigned short* __restrict__ P,
    unsigned short* __restrict__ attn)
{
    extern __shared__ unsigned short lds_raw[];
    const int nwg = gridDim.x * gridDim.y;            // 256
    const int bid = blockIdx.y * gridDim.x + blockIdx.x;
    const int vbk = (bid & 7) * (nwg >> 3) + (bid >> 3);
    const int bn  = (vbk & 3) * 256;
    const int bm  = (vbk >> 2) * 256;                 // over 16384
    const int batch = bm >> 11, am0 = bm & 2047;
    gemm256(Vp + (long)batch * 2048 * 1024, P + (long)batch * 1024 * 2048,
            nullptr, attn, 1024, 1024, 1024, 2048, 2048, am0,
            (long)batch * 2048 * 1024, bn, 1.f, 0, 0, lds_raw);
}

__global__ __launch_bounds__(512, 2) void k_out(
    const unsigned short* __restrict__ attn, const unsigned short* __restrict__ wob,
    const float* __restrict__ bias4, void* __restrict__ Cv,
    const int* __restrict__ flagp)
{
    extern __shared__ unsigned short lds_raw[];
    const int nwg = gridDim.x * gridDim.y;            // 256
    const int bid = blockIdx.y * gridDim.x + blockIdx.x;
    const int vbk = (bid & 7) * (nwg >> 3) + (bid >> 3);
    const int bn  = (vbk & 3) * 256;
    const int bm  = (vbk >> 2) * 256;                 // over 16384
    gemm256(attn, wob, bias4 + 3 * 1024, Cv, 1024, 1024, 1024, 1024,
            16384, bm, 0, bn, 1.f, 3, flagp[0], lds_raw);
}

// ---------------- scores: 128x256, BK=32, 48KB LDS (CONTROL, unchanged) ----
__global__ __launch_bounds__(512, 4) void k_scores(
    const unsigned short* __restrict__ Qt, const unsigned short* __restrict__ Kt,
    float* __restrict__ S)
{
    extern __shared__ unsigned short lds_raw[];   // 2 x 12288 shorts
    const int tid  = threadIdx.x;
    const int lane = tid & 63;
    const int wave = tid >> 6;
    const int nwg = gridDim.x * gridDim.y;        // 256
    const int bid = blockIdx.y * gridDim.x + blockIdx.x;
    const int vbk = (bid & 7) * (nwg >> 3) + (bid >> 3);
    const int bn  = (vbk & 3) * 256;
    const int bm  = (vbk >> 2) * 128;             // over 8192
    const int batch = bm >> 10, am0 = bm & 1023;
    const unsigned short* Ab = Qt + (long)batch * 1024 * 2048;
    const unsigned short* Bb = Kt + (long)batch * 1024 * 2048;
    const long zC = (long)batch * 1024 * 1024;
    const int wm = (wave >> 2) * 64;
    const int wn = (wave & 3) * 64;

    f32x4 acc[4][4];
    const f32x4 zero = {0.f, 0.f, 0.f, 0.f};
#pragma unroll
    for (int i = 0; i < 4; ++i)
#pragma unroll
        for (int j = 0; j < 4; ++j) acc[i][j] = zero;

    auto stage = [&](int kt, int cb) {
        unsigned short* Lb = lds_raw + (size_t)cb * 12288;
        {
            const int c = tid, row = c >> 2;
            const int klo = (c & 3) ^ ((row >> 1) & 3);
            gld16(Ab + (long)(am0 + row) * 2048 + kt * 32 + klo * 8, Lb + (size_t)c * 8);
        }
#pragma unroll
        for (int j = 0; j < 2; ++j) {
            const int c = j * 512 + tid, row = c >> 2;
            const int klo = (c & 3) ^ ((row >> 1) & 3);
            gld16(Bb + (long)(bn + row) * 2048 + kt * 32 + klo * 8, Lb + 4096 + (size_t)c * 8);
        }
    };
    auto ctile = [&](int cb) {
        const unsigned short* LA = lds_raw + (size_t)cb * 12288;
        const unsigned short* LB = LA + 4096;
        const int kl = lane >> 4;
        b16x8 af[4], bf[4];
#pragma unroll
        for (int j = 0; j < 4; ++j) {
            const int r = wn + j * 16 + (lane & 15);
            bf[j] = *(const b16x8*)(LB + ((size_t)r * 4 + (kl ^ ((r >> 1) & 3))) * 8);
        }
#pragma unroll
        for (int i = 0; i < 4; ++i) {
            const int r = wm + i * 16 + (lane & 15);
            af[i] = *(const b16x8*)(LA + ((size_t)r * 4 + (kl ^ ((r >> 1) & 3))) * 8);
        }
#pragma unroll
        for (int i = 0; i < 4; ++i)
#pragma unroll
            for (int j = 0; j < 4; ++j)
                acc[i][j] = __builtin_amdgcn_mfma_f32_16x16x32_bf16(af[i], bf[j], acc[i][j], 0, 0, 0);
    };

    const int NT = 2048 >> 5;
    stage(0, 0);
    __syncthreads();
    int cur = 0;
    for (int kt = 0; kt < NT - 1; ++kt) {
        stage(kt + 1, cur ^ 1);
        ctile(cur);
        __syncthreads();
        cur ^= 1;
    }
    ctile(cur);

#pragma unroll
    for (int i = 0; i < 4; ++i)
#pragma unroll
        for (int j = 0; j < 4; ++j) {
            const int rloc = am0 + wm + i * 16 + (lane >> 4) * 4;
            const int n    = bn + wn + j * 16 + (lane & 15);
#pragma unroll
            for (int r = 0; r < 4; ++r)
                S[zC + (long)(rloc + r) * 1024 + n] = acc[i][j][r] * 0.125f;
        }
}

// ---------------- row softmax over 1024 cols, IN-PLACE ----------------
__global__ __launch_bounds__(256) void k_softmax(float* __restrict__ S) {
    const long row = blockIdx.x;
    float* s = S + row * 1024;
    unsigned short* p = (unsigned short*)s;
    const int tid = threadIdx.x;
    float4 v = ((const float4*)s)[tid];
    float m = fmaxf(fmaxf(v.x, v.y), fmaxf(v.z, v.w));
#pragma unroll
    for (int o = 32; o > 0; o >>= 1) m = fmaxf(m, __shfl_xor(m, o));
    __shared__ float sm[4], ss[4];
    if ((tid & 63) == 0) sm[tid >> 6] = m;
    __syncthreads();
    m = fmaxf(fmaxf(sm[0], sm[1]), fmaxf(sm[2], sm[3]));
    float e0 = __expf(v.x - m), e1 = __expf(v.y - m);
    float e2 = __expf(v.z - m), e3 = __expf(v.w - m);
    float sum = e0 + e1 + e2 + e3;
#pragma unroll
    for (int o = 32; o > 0; o >>= 1) sum += __shfl_xor(sum, o);
    if ((tid & 63) == 0) ss[tid >> 6] = sum;
    __syncthreads();
    float inv = 1.f / (ss[0] + ss[1] + ss[2] + ss[3]);
    uint32_t w0 = f2bf(e0 * inv) | ((uint32_t)f2bf(e1 * inv) << 16);
    uint32_t w1 = f2bf(e2 * inv) | ((uint32_t)f2bf(e3 * inv) << 16);
    uint2 val; val.x = w0; val.y = w1;
    *(uint2*)(p + tid * 4) = val;
}

// ---------------- host ----------------
extern "C" void kernel_launch(void* const* d_in, const int* in_sizes, int n_in,
                              void* d_out, int out_size, void* d_ws, size_t ws_size,
                              hipStream_t stream) {
    (void)in_sizes; (void)n_in; (void)out_size; (void)ws_size;
    const void* q_in = d_in[0];
    const void* k_in = d_in[1];
    const void* v_in = d_in[2];
    const void* Wq   = d_in[3];
    const void* bq   = d_in[4];
    const void* Wk   = d_in[5];
    const void* bk   = d_in[6];
    const void* Wv   = d_in[7];
    const void* bv   = d_in[8];
    const void* Wo   = d_in[9];
    const void* bo   = d_in[10];

    const size_t MB = 1u << 20;
    const size_t LDS_BIG = 131072, LDS_S = 49152;
    hipFuncSetAttribute((const void*)k_proj3,  hipFuncAttributeMaxDynamicSharedMemorySize, (int)LDS_BIG);
    hipFuncSetAttribute((const void*)k_attn,   hipFuncAttributeMaxDynamicSharedMemorySize, (int)LDS_BIG);
    hipFuncSetAttribute((const void*)k_out,    hipFuncAttributeMaxDynamicSharedMemorySize, (int)LDS_BIG);
    hipFuncSetAttribute((const void*)k_scores, hipFuncAttributeMaxDynamicSharedMemorySize, (int)LDS_S);

    // workspace (97 MB proven): flag 1MB + R1(32) + R2(32) + R3(32)
    // R1: kb -> scores/P.  R2: vb == Vp == attn (in-place).  R3: weights+bias+qb.
    // d_out: Kt [0,32) + Qt [32,64) bf16 scratch -> final f32 overwrites.
    char* ws = (char*)d_ws;
    int*            flag = (int*)ws;
    unsigned short* R1   = (unsigned short*)(ws + 1 * MB);
    unsigned short* R2   = (unsigned short*)(ws + 33 * MB);
    char*           R3   = ws + 65 * MB;
    unsigned short* kb = R1;
    unsigned short* vb = R2, *Vp = R2, *attn = R2;
    float*          scores = (float*)R1;
    unsigned short* P      = R1;                         // row i at i*2048 shorts
    unsigned short* wqb = (unsigned short*)R3;           // 1MB
    unsigned short* wkb = (unsigned short*)(R3 + 1 * MB);
    unsigned short* wvb = (unsigned short*)(R3 + 3 * MB);
    unsigned short* wob = (unsigned short*)(R3 + 5 * MB);
    float*          bias4 = (float*)(R3 + 7 * MB);
    unsigned short* qb  = (unsigned short*)(R3 + 8 * MB); // 16MB
    unsigned short* Kt = (unsigned short*)d_out;
    unsigned short* Qt = (unsigned short*)((char*)d_out + 32 * MB);

    dim3 blk(256), blk5(512);
    // 1) prep: flag + biases + weights + k/q/v cvt (one dispatch)
    k_prep<<<dim3(2048), blk, 0, stream>>>(
        q_in, k_in, v_in, Wq, bq, Wk, bk, Wv, bv, Wo, bo,
        wqb, wkb, wvb, wob, bias4, kb, qb, vb, flag);
    // 2) merged projections: Kt, Qt (transposed), Vp (in-place over vb)
    k_proj3<<<dim3(4, 192), blk5, LDS_BIG, stream>>>(
        kb, qb, vb, wkb, wqb, wvb, bias4, Kt, Qt, Vp);
    // 3) scores (control, unchanged): S = (1/8) Qt.Kt^T -> f32 in R1
    k_scores<<<dim3(4, 64), blk5, LDS_S, stream>>>(Qt, Kt, scores);
    // 4) softmax in-place -> P
    k_softmax<<<dim3(8192), blk, 0, stream>>>(scores);
    // 5) attn = Vp . P^T (in-place over Vp)
    k_attn<<<dim3(4, 64), blk5, LDS_BIG, stream>>>(Vp, P, attn);
    // 6) out = attn@Wo^T + bo -> d_out (f32 per flag)
    k_out<<<dim3(4, 64), blk5, LDS_BIG, stream>>>(attn, wob, bias4, d_out, flag);
}

// Round 17
// 281.001 us; speedup vs baseline: 1.0717x; 1.0717x over previous
//
#include <hip/hip_runtime.h>
#include <hip/hip_bf16.h>
#include <stdint.h>

// ---------------- types / helpers ----------------
typedef __bf16 b16x8 __attribute__((ext_vector_type(8)));
typedef float  f32x4 __attribute__((ext_vector_type(4)));

__device__ __forceinline__ unsigned short f2bf(float f) {
    uint32_t u = __float_as_uint(f);
    u += 0x7fffu + ((u >> 16) & 1u);   // RNE
    return (unsigned short)(u >> 16);
}
__device__ __forceinline__ float bf2f(unsigned short s) {
    return __uint_as_float(((uint32_t)s) << 16);
}

__device__ __forceinline__ void gld16(const unsigned short* g, unsigned short* l) {
    __builtin_amdgcn_global_load_lds(
        (const __attribute__((address_space(1))) void*)g,
        (__attribute__((address_space(3))) void*)l, 16, 0, 0);
}

// convert/copy one 8-elem chunk (16B bf16 out)
__device__ __forceinline__ void cvt_chunk(const void* src, unsigned short* dst,
                                          long off, int fl) {
    if (fl) {
        const float4* s = (const float4*)src + 2 * off;
        float4 a = s[0], b = s[1];
        uint4 o;
        o.x = f2bf(a.x) | ((uint32_t)f2bf(a.y) << 16);
        o.y = f2bf(a.z) | ((uint32_t)f2bf(a.w) << 16);
        o.z = f2bf(b.x) | ((uint32_t)f2bf(b.y) << 16);
        o.w = f2bf(b.z) | ((uint32_t)f2bf(b.w) << 16);
        ((uint4*)dst)[off] = o;
    } else {
        ((uint4*)dst)[off] = ((const uint4*)src)[off];
    }
}

// ---------------- prep: flag + biases + weights + k/q/v cvt (1 dispatch) ---
__global__ __launch_bounds__(256) void k_prep(
    const void* __restrict__ q_in, const void* __restrict__ k_in,
    const void* __restrict__ v_in,
    const void* Wq, const void* bq, const void* Wk, const void* bk,
    const void* Wv, const void* bv, const void* Wo, const void* bo,
    unsigned short* __restrict__ wqb, unsigned short* __restrict__ wkb,
    unsigned short* __restrict__ wvb, unsigned short* __restrict__ wob,
    float* __restrict__ bias4,
    unsigned short* __restrict__ kb, unsigned short* __restrict__ qb,
    unsigned short* __restrict__ vb, int* __restrict__ flag)
{
    // local dtype flag (pure function of q's first 4096 u16 -> deterministic)
    float m = 0.f;
    const unsigned short* qraw = (const unsigned short*)q_in;
    for (int i = threadIdx.x; i < 4096; i += 256) {
        float f = fabsf(bf2f(qraw[i]));
        if (!(f < 1e30f)) f = 1e30f;
        m = fmaxf(m, f);
    }
#pragma unroll
    for (int o = 32; o > 0; o >>= 1) m = fmaxf(m, __shfl_xor(m, o));
    __shared__ float red[4];
    if ((threadIdx.x & 63) == 0) red[threadIdx.x >> 6] = m;
    __syncthreads();
    m = fmaxf(fmaxf(red[0], red[1]), fmaxf(red[2], red[3]));
    const int fl = (m > 1e6f) ? 1 : 0;   // 1 => inputs are f32
    if (blockIdx.x == 0 && threadIdx.x == 0) flag[0] = fl;

    if (blockIdx.x < 16) {   // biases -> f32
        int i = blockIdx.x * 256 + threadIdx.x;
        int which = i >> 10, idx = i & 1023;
        const void* src = (which == 0) ? bq : (which == 1) ? bk : (which == 2) ? bv : bo;
        bias4[i] = fl ? ((const float*)src)[idx] : bf2f(((const unsigned short*)src)[idx]);
    }

    const long NW = 65536L + 3 * 131072L;   // weight 8-elem chunks
    for (long c = blockIdx.x * 256L + threadIdx.x; c < NW; c += (long)gridDim.x * 256L) {
        if (c < 65536)       cvt_chunk(Wq, wqb, c, fl);
        else if (c < 196608) cvt_chunk(Wk, wkb, c - 65536, fl);
        else if (c < 327680) cvt_chunk(Wv, wvb, c - 196608, fl);
        else                 cvt_chunk(Wo, wob, c - 327680, fl);
    }

    const long KN8 = 2097152, QN8 = 1048576, VN8 = 2097152;
    const long TOT = KN8 + QN8 + VN8;
    for (long c = blockIdx.x * 256L + threadIdx.x; c < TOT; c += (long)gridDim.x * 256L) {
        if (c < KN8)            cvt_chunk(k_in, kb, c, fl);
        else if (c < KN8 + QN8) cvt_chunk(q_in, qb, c - KN8, fl);
        else                    cvt_chunk(v_in, vb, c - KN8 - QN8, fl);
    }
}

// ---------------- 256x256 BK=64 GEMM core (2-barrier, gld_lds) ------------
// No setprio (m190: hurts lockstep structures). MFMA order q,s,j: acc reuse
// distance 4 (dependent-MFMA chain spacing).
__device__ __forceinline__ void gemm256(
    const unsigned short* __restrict__ Ab, const unsigned short* __restrict__ Bb,
    const float* __restrict__ bias, void* __restrict__ Cv,
    int N, int K, int ldA, int ldB, int Mb, int am0, long zC, int bn,
    float scale, int mode, int fl, unsigned short* lds)
{
    const int tid  = threadIdx.x;
    const int lane = tid & 63;
    const int wave = tid >> 6;
    const int wm = (wave >> 2) * 128;
    const int wn = (wave & 3) * 64;

    f32x4 acc[8][4];
    const f32x4 zero = {0.f, 0.f, 0.f, 0.f};
#pragma unroll
    for (int i = 0; i < 8; ++i)
#pragma unroll
        for (int j = 0; j < 4; ++j) acc[i][j] = zero;

    auto stage = [&](int kt, int cb) {
        unsigned short* LA = lds + (size_t)cb * 32768;
        unsigned short* LB = LA + 16384;
#pragma unroll
        for (int j = 0; j < 4; ++j) {
            const int d = j * 512 + tid;
            const int row = d >> 3;
            const int klo = (d & 7) ^ (row & 7);
            gld16(Ab + (long)(am0 + row) * ldA + kt * 64 + klo * 8, LA + (size_t)d * 8);
            gld16(Bb + (long)(bn + row) * ldB + kt * 64 + klo * 8, LB + (size_t)d * 8);
        }
    };
    auto ctile = [&](int cb) {
        const unsigned short* LA = lds + (size_t)cb * 32768;
        const unsigned short* LB = LA + 16384;
        b16x8 bfr[4][2];
#pragma unroll
        for (int p = 0; p < 4; ++p) {
            if (p == 0) {
#pragma unroll
                for (int j = 0; j < 4; ++j)
#pragma unroll
                    for (int s = 0; s < 2; ++s) {
                        const int r = wn + j * 16 + (lane & 15);
                        const int kl = s * 4 + (lane >> 4);
                        bfr[j][s] = *(const b16x8*)(LB + ((size_t)r * 8 + (kl ^ (r & 7))) * 8);
                    }
            }
            b16x8 a[2][2];
#pragma unroll
            for (int q = 0; q < 2; ++q)
#pragma unroll
                for (int s = 0; s < 2; ++s) {
                    const int r = wm + (2 * p + q) * 16 + (lane & 15);
                    const int kl = s * 4 + (lane >> 4);
                    a[q][s] = *(const b16x8*)(LA + ((size_t)r * 8 + (kl ^ (r & 7))) * 8);
                }
            // q,s,j order: same-acc MFMAs are 4 apart (was adjacent)
#pragma unroll
            for (int q = 0; q < 2; ++q)
#pragma unroll
                for (int s = 0; s < 2; ++s)
#pragma unroll
                    for (int j = 0; j < 4; ++j)
                        acc[2 * p + q][j] = __builtin_amdgcn_mfma_f32_16x16x32_bf16(
                            a[q][s], bfr[j][s], acc[2 * p + q][j], 0, 0, 0);
        }
    };

    const int NT = K >> 6;
    stage(0, 0);
    __syncthreads();
    int cur = 0;
    for (int kt = 0; kt < NT - 1; ++kt) {
        stage(kt + 1, cur ^ 1);
        ctile(cur);
        __syncthreads();
        cur ^= 1;
    }
    ctile(cur);

#pragma unroll
    for (int i = 0; i < 8; ++i)
#pragma unroll
        for (int j = 0; j < 4; ++j) {
            const int rloc = am0 + wm + i * 16 + (lane >> 4) * 4;
            const int n    = bn + wn + j * 16 + (lane & 15);
            const float bv = (mode != 2 && bias != nullptr) ? bias[n] : 0.f;
            if (mode == 0) {
                unsigned short* C = (unsigned short*)Cv;
#pragma unroll
                for (int r = 0; r < 4; ++r)
                    C[zC + (long)(rloc + r) * N + n] = f2bf(acc[i][j][r] * scale + bv);
            } else if (mode == 1) {
                unsigned short* C = (unsigned short*)Cv;
                uint32_t p0 = f2bf(acc[i][j][0] * scale + bv) |
                              ((uint32_t)f2bf(acc[i][j][1] * scale + bv) << 16);
                uint32_t p1 = f2bf(acc[i][j][2] * scale + bv) |
                              ((uint32_t)f2bf(acc[i][j][3] * scale + bv) << 16);
                uint2 val; val.x = p0; val.y = p1;
                *(uint2*)(C + zC + (long)n * Mb + rloc) = val;
            } else if (mode == 2) {
                float* C = (float*)Cv;
#pragma unroll
                for (int r = 0; r < 4; ++r)
                    C[zC + (long)(rloc + r) * N + n] = acc[i][j][r] * scale;
            } else {
                if (fl) {
                    float* C = (float*)Cv;
#pragma unroll
                    for (int r = 0; r < 4; ++r)
                        C[zC + (long)(rloc + r) * N + n] = acc[i][j][r] * scale + bv;
                } else {
                    unsigned short* C = (unsigned short*)Cv;
#pragma unroll
                    for (int r = 0; r < 4; ++r)
                        C[zC + (long)(rloc + r) * N + n] = f2bf(acc[i][j][r] * scale + bv);
                }
            }
        }
}

// ---------------- merged K/Q/V projections: 768 blocks, 1 dispatch ---------
__global__ __launch_bounds__(512, 2) void k_proj3(
    const unsigned short* __restrict__ kb, const unsigned short* __restrict__ qb,
    const unsigned short* __restrict__ vb,
    const unsigned short* __restrict__ wkb, const unsigned short* __restrict__ wqb,
    const unsigned short* __restrict__ wvb,
    const float* __restrict__ bias4,
    unsigned short* __restrict__ Kt, unsigned short* __restrict__ Qt,
    unsigned short* __restrict__ Vp)
{
    extern __shared__ unsigned short lds_raw[];
    const int nwg = gridDim.x * gridDim.y;            // 768
    const int bid = blockIdx.y * gridDim.x + blockIdx.x;
    const int vbk = (bid & 7) * (nwg >> 3) + (bid >> 3);
    const int sec = vbk >> 8;                         // 0:K 1:Q 2:V
    const int wi  = vbk & 255;
    const int bn  = (wi & 3) * 256;
    const int bm  = (wi >> 2) * 256;
    if (sec == 0) {
        const int batch = bm >> 11, am0 = bm & 2047;
        gemm256(kb + (long)batch * 2048 * 1024, wkb, bias4 + 1024, Kt,
                1024, 1024, 1024, 1024, 2048, am0, (long)batch * 1024 * 2048, bn,
                1.f, 1, 0, lds_raw);
    } else if (sec == 1) {
        const int batch = bm >> 11, am0 = bm & 2047;
        gemm256(qb + (long)batch * 2048 * 512, wqb, bias4, Qt,
                1024, 512, 512, 512, 2048, am0, (long)batch * 1024 * 2048, bn,
                1.f, 1, 0, lds_raw);
    } else {
        gemm256(vb, wvb, bias4 + 2 * 1024, Vp,
                1024, 1024, 1024, 1024, 16384, bm, 0, bn,
                1.f, 0, 0, lds_raw);                  // in-place (co-start timing-safe)
    }
}

// ---------------- attn and out (256x256 core) ----------------
__global__ __launch_bounds__(512, 2) void k_attn(
    const unsigned short* __restrict__ Vp, const unsigned short* __restrict__ P,
    unsigned short* __restrict__ attn)
{
    extern __shared__ unsigned short lds_raw[];
    const int nwg = gridDim.x * gridDim.y;            // 256
    const int bid = blockIdx.y * gridDim.x + blockIdx.x;
    const int vbk = (bid & 7) * (nwg >> 3) + (bid >> 3);
    const int bn  = (vbk & 3) * 256;
    const int bm  = (vbk >> 2) * 256;                 // over 16384
    const int batch = bm >> 11, am0 = bm & 2047;
    gemm256(Vp + (long)batch * 2048 * 1024, P + (long)batch * 1024 * 2048,
            nullptr, attn, 1024, 1024, 1024, 2048, 2048, am0,
            (long)batch * 2048 * 1024, bn, 1.f, 0, 0, lds_raw);
}

__global__ __launch_bounds__(512, 2) void k_out(
    const unsigned short* __restrict__ attn, const unsigned short* __restrict__ wob,
    const float* __restrict__ bias4, void* __restrict__ Cv,
    const int* __restrict__ flagp)
{
    extern __shared__ unsigned short lds_raw[];
    const int nwg = gridDim.x * gridDim.y;            // 256
    const int bid = blockIdx.y * gridDim.x + blockIdx.x;
    const int vbk = (bid & 7) * (nwg >> 3) + (bid >> 3);
    const int bn  = (vbk & 3) * 256;
    const int bm  = (vbk >> 2) * 256;                 // over 16384
    gemm256(attn, wob, bias4 + 3 * 1024, Cv, 1024, 1024, 1024, 1024,
            16384, bm, 0, bn, 1.f, 3, flagp[0], lds_raw);
}

// ---------------- scores: 128x256, BK=32, 48KB LDS, 256 blocks -------------
__global__ __launch_bounds__(512, 4) void k_scores(
    const unsigned short* __restrict__ Qt, const unsigned short* __restrict__ Kt,
    float* __restrict__ S)
{
    extern __shared__ unsigned short lds_raw[];   // 2 x 12288 shorts
    const int tid  = threadIdx.x;
    const int lane = tid & 63;
    const int wave = tid >> 6;
    const int nwg = gridDim.x * gridDim.y;        // 256
    const int bid = blockIdx.y * gridDim.x + blockIdx.x;
    const int vbk = (bid & 7) * (nwg >> 3) + (bid >> 3);
    const int bn  = (vbk & 3) * 256;
    const int bm  = (vbk >> 2) * 128;             // over 8192
    const int batch = bm >> 10, am0 = bm & 1023;
    const unsigned short* Ab = Qt + (long)batch * 1024 * 2048;
    const unsigned short* Bb = Kt + (long)batch * 1024 * 2048;
    const long zC = (long)batch * 1024 * 1024;
    const int wm = (wave >> 2) * 64;
    const int wn = (wave & 3) * 64;

    f32x4 acc[4][4];
    const f32x4 zero = {0.f, 0.f, 0.f, 0.f};
#pragma unroll
    for (int i = 0; i < 4; ++i)
#pragma unroll
        for (int j = 0; j < 4; ++j) acc[i][j] = zero;

    auto stage = [&](int kt, int cb) {
        unsigned short* Lb = lds_raw + (size_t)cb * 12288;
        {
            const int c = tid, row = c >> 2;
            const int klo = (c & 3) ^ ((row >> 1) & 3);
            gld16(Ab + (long)(am0 + row) * 2048 + kt * 32 + klo * 8, Lb + (size_t)c * 8);
        }
#pragma unroll
        for (int j = 0; j < 2; ++j) {
            const int c = j * 512 + tid, row = c >> 2;
            const int klo = (c & 3) ^ ((row >> 1) & 3);
            gld16(Bb + (long)(bn + row) * 2048 + kt * 32 + klo * 8, Lb + 4096 + (size_t)c * 8);
        }
    };
    auto ctile = [&](int cb) {
        const unsigned short* LA = lds_raw + (size_t)cb * 12288;
        const unsigned short* LB = LA + 4096;
        const int kl = lane >> 4;
        b16x8 af[4], bf[4];
#pragma unroll
        for (int j = 0; j < 4; ++j) {
            const int r = wn + j * 16 + (lane & 15);
            bf[j] = *(const b16x8*)(LB + ((size_t)r * 4 + (kl ^ ((r >> 1) & 3))) * 8);
        }
#pragma unroll
        for (int i = 0; i < 4; ++i) {
            const int r = wm + i * 16 + (lane & 15);
            af[i] = *(const b16x8*)(LA + ((size_t)r * 4 + (kl ^ ((r >> 1) & 3))) * 8);
        }
        // 16 independent accs -> order free; no setprio (lockstep)
#pragma unroll
        for (int i = 0; i < 4; ++i)
#pragma unroll
            for (int j = 0; j < 4; ++j)
                acc[i][j] = __builtin_amdgcn_mfma_f32_16x16x32_bf16(af[i], bf[j], acc[i][j], 0, 0, 0);
    };

    const int NT = 2048 >> 5;
    stage(0, 0);
    __syncthreads();
    int cur = 0;
    for (int kt = 0; kt < NT - 1; ++kt) {
        stage(kt + 1, cur ^ 1);
        ctile(cur);
        __syncthreads();
        cur ^= 1;
    }
    ctile(cur);

#pragma unroll
    for (int i = 0; i < 4; ++i)
#pragma unroll
        for (int j = 0; j < 4; ++j) {
            const int rloc = am0 + wm + i * 16 + (lane >> 4) * 4;
            const int n    = bn + wn + j * 16 + (lane & 15);
#pragma unroll
            for (int r = 0; r < 4; ++r)
                S[zC + (long)(rloc + r) * 1024 + n] = acc[i][j][r] * 0.125f;
        }
}

// ---------------- row softmax over 1024 cols, IN-PLACE ----------------
__global__ __launch_bounds__(256) void k_softmax(float* __restrict__ S) {
    const long row = blockIdx.x;
    float* s = S + row * 1024;
    unsigned short* p = (unsigned short*)s;
    const int tid = threadIdx.x;
    float4 v = ((const float4*)s)[tid];
    float m = fmaxf(fmaxf(v.x, v.y), fmaxf(v.z, v.w));
#pragma unroll
    for (int o = 32; o > 0; o >>= 1) m = fmaxf(m, __shfl_xor(m, o));
    __shared__ float sm[4], ss[4];
    if ((tid & 63) == 0) sm[tid >> 6] = m;
    __syncthreads();
    m = fmaxf(fmaxf(sm[0], sm[1]), fmaxf(sm[2], sm[3]));
    float e0 = __expf(v.x - m), e1 = __expf(v.y - m);
    float e2 = __expf(v.z - m), e3 = __expf(v.w - m);
    float sum = e0 + e1 + e2 + e3;
#pragma unroll
    for (int o = 32; o > 0; o >>= 1) sum += __shfl_xor(sum, o);
    if ((tid & 63) == 0) ss[tid >> 6] = sum;
    __syncthreads();
    float inv = 1.f / (ss[0] + ss[1] + ss[2] + ss[3]);
    uint32_t w0 = f2bf(e0 * inv) | ((uint32_t)f2bf(e1 * inv) << 16);
    uint32_t w1 = f2bf(e2 * inv) | ((uint32_t)f2bf(e3 * inv) << 16);
    uint2 val; val.x = w0; val.y = w1;
    *(uint2*)(p + tid * 4) = val;
}

// ---------------- host ----------------
extern "C" void kernel_launch(void* const* d_in, const int* in_sizes, int n_in,
                              void* d_out, int out_size, void* d_ws, size_t ws_size,
                              hipStream_t stream) {
    (void)in_sizes; (void)n_in; (void)out_size; (void)ws_size;
    const void* q_in = d_in[0];
    const void* k_in = d_in[1];
    const void* v_in = d_in[2];
    const void* Wq   = d_in[3];
    const void* bq   = d_in[4];
    const void* Wk   = d_in[5];
    const void* bk   = d_in[6];
    const void* Wv   = d_in[7];
    const void* bv   = d_in[8];
    const void* Wo   = d_in[9];
    const void* bo   = d_in[10];

    const size_t MB = 1u << 20;
    const size_t LDS_BIG = 131072, LDS_S = 49152;
    hipFuncSetAttribute((const void*)k_proj3,  hipFuncAttributeMaxDynamicSharedMemorySize, (int)LDS_BIG);
    hipFuncSetAttribute((const void*)k_attn,   hipFuncAttributeMaxDynamicSharedMemorySize, (int)LDS_BIG);
    hipFuncSetAttribute((const void*)k_out,    hipFuncAttributeMaxDynamicSharedMemorySize, (int)LDS_BIG);
    hipFuncSetAttribute((const void*)k_scores, hipFuncAttributeMaxDynamicSharedMemorySize, (int)LDS_S);

    // workspace (97 MB proven): flag 1MB + R1(32) + R2(32) + R3(32)
    // R1: kb -> scores/P.  R2: vb == Vp == attn (in-place).  R3: weights+bias+qb.
    // d_out: Kt [0,32) + Qt [32,64) bf16 scratch -> final f32 overwrites.
    char* ws = (char*)d_ws;
    int*            flag = (int*)ws;
    unsigned short* R1   = (unsigned short*)(ws + 1 * MB);
    unsigned short* R2   = (unsigned short*)(ws + 33 * MB);
    char*           R3   = ws + 65 * MB;
    unsigned short* kb = R1;
    unsigned short* vb = R2, *Vp = R2, *attn = R2;
    float*          scores = (float*)R1;
    unsigned short* P      = R1;                         // row i at i*2048 shorts
    unsigned short* wqb = (unsigned short*)R3;           // 1MB
    unsigned short* wkb = (unsigned short*)(R3 + 1 * MB);
    unsigned short* wvb = (unsigned short*)(R3 + 3 * MB);
    unsigned short* wob = (unsigned short*)(R3 + 5 * MB);
    float*          bias4 = (float*)(R3 + 7 * MB);
    unsigned short* qb  = (unsigned short*)(R3 + 8 * MB); // 16MB
    unsigned short* Kt = (unsigned short*)d_out;
    unsigned short* Qt = (unsigned short*)((char*)d_out + 32 * MB);

    dim3 blk(256), blk5(512);
    // 1) prep: flag + biases + weights + k/q/v cvt (one dispatch)
    k_prep<<<dim3(2048), blk, 0, stream>>>(
        q_in, k_in, v_in, Wq, bq, Wk, bk, Wv, bv, Wo, bo,
        wqb, wkb, wvb, wob, bias4, kb, qb, vb, flag);
    // 2) merged projections: Kt, Qt (transposed), Vp (in-place over vb)
    k_proj3<<<dim3(4, 192), blk5, LDS_BIG, stream>>>(
        kb, qb, vb, wkb, wqb, wvb, bias4, Kt, Qt, Vp);
    // 3) scores (full-machine 128x256): S = (1/8) Qt.Kt^T -> f32 in R1
    k_scores<<<dim3(4, 64), blk5, LDS_S, stream>>>(Qt, Kt, scores);
    // 4) softmax in-place -> P
    k_softmax<<<dim3(8192), blk, 0, stream>>>(scores);
    // 5) attn = Vp . P^T (in-place over Vp)
    k_attn<<<dim3(4, 64), blk5, LDS_BIG, stream>>>(Vp, P, attn);
    // 6) out = attn@Wo^T + bo -> d_out (f32 per flag)
    k_out<<<dim3(4, 64), blk5, LDS_BIG, stream>>>(attn, wob, bias4, d_out, flag);
}